// Round 3
// baseline (357.996 us; speedup 1.0000x reference)
//
#include <hip/hip_runtime.h>

// B=1024, S=200, D=64, C=256
// out[0] cluster_emb  [B,C,D] f32, out[1] cluster_mask [B,C,S] f32 (0/1)
#define NB 1024
#define NS 200
#define ND 64
#define NC 256

typedef float v4f __attribute__((ext_vector_type(4)));

// ---------------------------------------------------------------------------
// K1: mask writer. One block = (batch, 64-cluster tile). LDS = 800 B only ->
// occupancy is wave-limited (8 blocks/CU), not LDS-limited. Pure store stream.
// ---------------------------------------------------------------------------
__global__ __launch_bounds__(256) void s3rec_mask_kernel(
    const int* __restrict__ labels,  // [B,S]
    const int* __restrict__ amask,   // [B,S]
    float* __restrict__ out_mask)    // [B,C,S]
{
    __shared__ __align__(16) int s_lab[NS];

    const int bid = blockIdx.x;
    const int b   = bid >> 2;          // batch
    const int ct  = (bid & 3) << 6;    // cluster tile base (0,64,128,192)
    const int t   = threadIdx.x;

    for (int i = t; i < NS; i += 256) {
        const int l = labels[b * NS + i];
        const int m = amask [b * NS + i];
        s_lab[i] = (m != 0) ? l : -1;
    }
    __syncthreads();

    // 64 clusters x 200 seq = 12800 floats = 3200 vec4 per block.
    // i4: c_local = i4/50, s-chunk = i4%50 (S=200 -> 50 vec4 per row).
    const int4* lab4 = reinterpret_cast<const int4*>(s_lab);
    v4f* om4 = reinterpret_cast<v4f*>(out_mask + (size_t)b * (NC * NS)) + ct * 50;
    for (int i4 = t; i4 < 64 * 50; i4 += 256) {
        const int cl = i4 / 50;
        const int s4 = i4 - cl * 50;
        const int c  = ct + cl;
        const int4 L = lab4[s4];           // ds_read_b128
        v4f v;
        v.x = (L.x == c) ? 1.0f : 0.0f;
        v.y = (L.y == c) ? 1.0f : 0.0f;
        v.z = (L.z == c) ? 1.0f : 0.0f;
        v.w = (L.w == c) ? 1.0f : 0.0f;
        __builtin_nontemporal_store(v, &om4[i4]);  // consecutive lanes -> 1KB/wave
    }
}

// ---------------------------------------------------------------------------
// K2: per-cluster mean embeddings. One block per batch; 64 KB LDS accumulator
// (2 blocks/CU). Traffic: 52 MB x-reads + 67 MB emb-stores.
// ---------------------------------------------------------------------------
__global__ __launch_bounds__(256) void s3rec_emb_kernel(
    const float* __restrict__ x,       // [B,S,D]
    const int*   __restrict__ labels,  // [B,S]
    const int*   __restrict__ amask,   // [B,S]
    float* __restrict__ out_emb)       // [B,C,D]
{
    __shared__ __align__(16) float s_emb[NC * ND];   // 65536 B
    __shared__ int   s_lab[NS];
    __shared__ float s_inv[NC];

    const int b = blockIdx.x;
    const int t = threadIdx.x;

    for (int i = t; i < NS; i += 256) {
        const int l = labels[b * NS + i];
        const int m = amask [b * NS + i];
        s_lab[i] = (m != 0) ? l : -1;
    }
    // zero accumulator with b128 writes (16 iters/thread)
    v4f* se4 = reinterpret_cast<v4f*>(s_emb);
    for (int i = t; i < (NC * ND) / 4; i += 256) {
        v4f z = {0.0f, 0.0f, 0.0f, 0.0f};
        se4[i] = z;
    }
    __syncthreads();

    // Wave w takes s = w, w+4, ...; lane = d. Loads: 256B/wave coalesced.
    // LDS atomicAdd: 64 consecutive floats -> 2 lanes/bank (free).
    const int lane = t & 63;
    const int w    = t >> 6;
    const float* xb = x + (size_t)b * NS * ND;
    for (int s = w; s < NS; s += 4) {
        const int c = s_lab[s];
        if (c >= 0) {
            atomicAdd(&s_emb[c * ND + lane], xb[s * ND + lane]);
        }
    }

    // thread t counts cluster t (broadcast LDS reads)
    int cnt = 0;
    #pragma unroll 8
    for (int s = 0; s < NS; ++s) cnt += (s_lab[s] == t) ? 1 : 0;
    s_inv[t] = (cnt > 0) ? (1.0f / (float)cnt) : 0.0f;
    __syncthreads();

    // scaled vec4 store; cluster of vec4 i4 = i4/16
    v4f* oe4 = reinterpret_cast<v4f*>(out_emb + (size_t)b * (NC * ND));
    for (int i4 = t; i4 < (NC * ND) / 4; i4 += 256) {
        const float inv = s_inv[i4 >> 4];
        v4f v = se4[i4] * inv;
        __builtin_nontemporal_store(v, &oe4[i4]);
    }
}

extern "C" void kernel_launch(void* const* d_in, const int* in_sizes, int n_in,
                              void* d_out, int out_size, void* d_ws, size_t ws_size,
                              hipStream_t stream) {
    const float* x      = (const float*)d_in[0];  // [B,S,D] f32
    const int*   labels = (const int*)  d_in[1];  // [B,S]   i32
    const int*   amask  = (const int*)  d_in[2];  // [B,S]   i32

    float* out_emb  = (float*)d_out;                   // [B,C,D]
    float* out_mask = out_emb + (size_t)NB * NC * ND;  // [B,C,S]

    s3rec_mask_kernel<<<dim3(NB * 4), dim3(256), 0, stream>>>(labels, amask, out_mask);
    s3rec_emb_kernel <<<dim3(NB),     dim3(256), 0, stream>>>(x, labels, amask, out_emb);
}